// Round 7
// baseline (236.115 us; speedup 1.0000x reference)
//
#include <hip/hip_runtime.h>

#define B 64
#define T 512
#define E 512
#define H 64
#define NEG_INF (-1e30f)

#define PBM 64        // proj block M tile
#define PBK 64        // proj K chunk
#define PN 192        // proj output cols (q|k|v)
#define NCHK (E / PBK)
#define NUNIT 40      // causal (chunk,strip32) units per batch: 16+12+8+4
#define GRID ((B * T) / PBM)   // 512 blocks = 2/CU, all co-resident

using short8 = __attribute__((ext_vector_type(8))) short;
using f32x16 = __attribute__((ext_vector_type(16))) float;

__device__ __forceinline__ unsigned short f2bf(float f) {
    unsigned int u = __float_as_uint(f);
    u += 0x7fffu + ((u >> 16) & 1u);
    return (unsigned short)(u >> 16);
}
__device__ __forceinline__ float bf2f(unsigned short s) {
    return __uint_as_float((unsigned int)s << 16);
}
__device__ __forceinline__ unsigned int bfpack_tr(float lo, float hi) {
    return (__float_as_uint(hi) & 0xffff0000u) | (__float_as_uint(lo) >> 16);
}
__device__ __forceinline__ void async_copy16(const void* g, void* l) {
    __builtin_amdgcn_global_load_lds(
        (const __attribute__((address_space(1))) unsigned int*)g,
        (__attribute__((address_space(3))) unsigned int*)l, 16, 0, 0);
}

#define AQ __ATOMIC_ACQUIRE
#define RL __ATOMIC_RELEASE
#define RX __ATOMIC_RELAXED
#define SCOPE __HIP_MEMORY_SCOPE_AGENT

// ---------------------------------------------------------------------------
// Persistent fused kernel: prep | proj | attention units | combine, with
// fine-grained flags so phases overlap across batches.  Grid 512 x 256,
// __launch_bounds__(256,2) + 64KB LDS -> exactly 2 blocks/CU, all resident.
// ---------------------------------------------------------------------------
__global__ __launch_bounds__(256, 2) void fused(
    const float* __restrict__ x,
    const float* __restrict__ Wq, const float* __restrict__ Wk,
    const float* __restrict__ Wv, const int* __restrict__ am,
    unsigned short* __restrict__ qbf, unsigned short* __restrict__ kbf,
    unsigned short* __restrict__ vT, unsigned short* __restrict__ WT_swz,
    unsigned int* __restrict__ mbits,
    unsigned short* __restrict__ O_part,
    float* __restrict__ m_part, float* __restrict__ l_part,
    float* __restrict__ out, unsigned int* __restrict__ sync)
{
    __shared__ unsigned short Xs[2][PBM * 64];   // 2 x 8 KB
    __shared__ unsigned short Ws2[2][PN * 64];   // 2 x 24 KB

    const int tid  = threadIdx.x;
    const int bid  = blockIdx.x;
    const int wid  = tid >> 6;
    const int lane = tid & 63;
    const int hi   = lane >> 5;
    const int r    = lane & 31;

    unsigned int* wbar = sync;          // 1
    unsigned int* bcnt = sync + 1;      // 64: proj blocks done per batch
    unsigned int* gcnt = sync + 1 + B;  // 256: attn units done per (b,g)

    // ================= phase 0: W swizzle + mask bitmask ==================
    if (tid < 192) {
        const int i = bid * 192 + tid;           // 512*192 = 98304 = PN*E
        const int c   = i / (PN * 64);
        const int rem = i - c * (PN * 64);
        const int row = rem >> 6;
        const int s   = rem & 63;
        const int klocal = s ^ ((row & 7) << 3);
        const int k   = c * 64 + klocal;
        const int seg = row >> 6, hh = row & 63;
        const float* W = (seg == 0) ? Wq : (seg == 1) ? Wk : Wv;
        WT_swz[i] = f2bf(W[(size_t)k * H + hh]);
    }
    if (bid < 128) {
        const int i = bid * 256 + tid;           // 128*256 = 32768 = B*T
        const unsigned long long bal = __ballot(am[i] != 0);
        if (lane == 0)       mbits[i >> 5] = (unsigned int)bal;
        else if (lane == 32) mbits[i >> 5] = (unsigned int)(bal >> 32);
    }
    __syncthreads();                    // drain this block's phase-0 stores
    if (tid == 0) {
        __hip_atomic_fetch_add(wbar, 1u, RL, SCOPE);
        while (__hip_atomic_load(wbar, RX, SCOPE) < (unsigned)GRID)
            __builtin_amdgcn_s_sleep(2);
        (void)__hip_atomic_load(wbar, AQ, SCOPE);   // acquire: inv caches
    }
    __syncthreads();

    // ================= phase A: projection GEMM (R6 dbuf body) ===========
    {
        const int row0 = bid * PBM;
        const int mrow  = (wid >> 1) * 32 + r;
        const int cbase = (wid & 1) * 96;

        const int aBase = mrow * 128;
        const int aXor  = (mrow & 7) << 4;
        int bBase[3], bXor[3];
        #pragma unroll
        for (int nt = 0; nt < 3; ++nt) {
            const int col = cbase + nt * 32 + r;
            bBase[nt] = col * 128;
            bXor[nt]  = (col & 7) << 4;
        }
        const int xs_rr[2]  = { tid >> 3, (256 + tid) >> 3 };
        const int xs_s16[2] = { tid & 7, tid & 7 };

        f32x16 acc[3] = {};

        // prologue: stage chunk 0 into buffer 0
        {
            #pragma unroll
            for (int p = 0; p < 6; ++p) {
                const int u = p * 256 + wid * 64 + lane;
                async_copy16(WT_swz + u * 8,
                             (char*)(&Ws2[0][0]) + (p * 256 + wid * 64) * 16);
            }
            #pragma unroll
            for (int p = 0; p < 2; ++p) {
                const int rr = xs_rr[p], s16 = xs_s16[p];
                const float4* src = reinterpret_cast<const float4*>(
                    &x[(size_t)(row0 + rr) * E + s16 * 8]);
                const float4 a0 = src[0], a1 = src[1];
                union { unsigned short us[8]; short8 v; } pk;
                pk.us[0] = f2bf(a0.x); pk.us[1] = f2bf(a0.y);
                pk.us[2] = f2bf(a0.z); pk.us[3] = f2bf(a0.w);
                pk.us[4] = f2bf(a1.x); pk.us[5] = f2bf(a1.y);
                pk.us[6] = f2bf(a1.z); pk.us[7] = f2bf(a1.w);
                const int cb = (s16 * 16) ^ ((rr & 7) << 4);
                *reinterpret_cast<short8*>((char*)(&Xs[0][0]) + rr * 128 + cb) = pk.v;
            }
            __syncthreads();
        }

        for (int c = 0; c < NCHK; ++c) {
            const int cur = c & 1;
            const bool pre = (c + 1 < NCHK);
            float4 xa[2], xb[2];

            if (pre) {
                const unsigned short* gw = WT_swz + (size_t)(c + 1) * (PN * 64);
                #pragma unroll
                for (int p = 0; p < 6; ++p) {
                    const int u = p * 256 + wid * 64 + lane;
                    async_copy16(gw + u * 8,
                                 (char*)(&Ws2[cur ^ 1][0]) + (p * 256 + wid * 64) * 16);
                }
                const int kc = (c + 1) * PBK;
                #pragma unroll
                for (int p = 0; p < 2; ++p) {
                    const float4* src = reinterpret_cast<const float4*>(
                        &x[(size_t)(row0 + xs_rr[p]) * E + kc + xs_s16[p] * 8]);
                    xa[p] = src[0];
                    xb[p] = src[1];
                }
            }

            #pragma unroll
            for (int ks = 0; ks < 4; ++ks) {
                const int koff = ks * 32 + hi * 16;
                const short8 a = *reinterpret_cast<const short8*>(
                    (const char*)(&Xs[cur][0]) + aBase + (koff ^ aXor));
                #pragma unroll
                for (int nt = 0; nt < 3; ++nt) {
                    const short8 b = *reinterpret_cast<const short8*>(
                        (const char*)(&Ws2[cur][0]) + bBase[nt] + (koff ^ bXor[nt]));
                    acc[nt] = __builtin_amdgcn_mfma_f32_32x32x16_bf16(a, b, acc[nt], 0, 0, 0);
                }
            }

            if (pre) {
                #pragma unroll
                for (int p = 0; p < 2; ++p) {
                    const int rr = xs_rr[p], s16 = xs_s16[p];
                    union { unsigned short us[8]; short8 v; } pk;
                    pk.us[0] = f2bf(xa[p].x); pk.us[1] = f2bf(xa[p].y);
                    pk.us[2] = f2bf(xa[p].z); pk.us[3] = f2bf(xa[p].w);
                    pk.us[4] = f2bf(xb[p].x); pk.us[5] = f2bf(xb[p].y);
                    pk.us[6] = f2bf(xb[p].z); pk.us[7] = f2bf(xb[p].w);
                    const int cb = (s16 * 16) ^ ((rr & 7) << 4);
                    *reinterpret_cast<short8*>((char*)(&Xs[cur ^ 1][0]) + rr * 128 + cb) = pk.v;
                }
            }
            __syncthreads();
        }

        // epilogue: q bf16 (pre-scaled 1/8), k bf16, v transposed
        #pragma unroll
        for (int nt = 0; nt < 3; ++nt) {
            const int gc  = cbase + nt * 32 + r;
            const int seg = gc >> 6;
            const int hh  = gc & 63;
            #pragma unroll
            for (int reg = 0; reg < 16; ++reg) {
                const int drow = (reg & 3) + 8 * (reg >> 2) + 4 * hi;
                const int grow = row0 + (wid >> 1) * 32 + drow;
                const float val = acc[nt][reg];
                if (seg == 0) {
                    qbf[(size_t)grow * H + hh] = f2bf(val * 0.125f);
                } else if (seg == 1) {
                    kbf[(size_t)grow * H + hh] = f2bf(val);
                } else {
                    const int bb = grow >> 9, tt = grow & 511;
                    vT[((size_t)bb * H + hh) * T + tt] = f2bf(val);
                }
            }
        }
    }
    __syncthreads();   // drain ALL threads' qkv stores into L2
    if (tid == 0)
        __hip_atomic_fetch_add(&bcnt[bid >> 3], 1u, RL, SCOPE);  // flush + signal

    // ================= phase B: attention units (R6 body, 2 per wave) =====
    const int gw = bid * 4 + wid;
    for (int pass = 0; pass < 2; ++pass) {
        int u;
        if (pass == 0) u = gw;
        else { if (gw >= 2560 - 2048) break; u = gw + 2048; }

        const int b = u / NUNIT;
        const int t = u - b * NUNIT;
        int c, qs;
        if (t < 16)      { c = 0; qs = t; }
        else if (t < 28) { c = 1; qs = t - 12; }
        else if (t < 36) { c = 2; qs = t - 20; }
        else             { c = 3; qs = t - 24; }
        const int t0    = qs * 32;
        const int kbase = c * 128;
        const int tq    = t0 + r;
        const int nkb   = min(4, ((t0 + 31 - kbase) >> 5) + 1);
        const bool diag = (kbase + 128 > t0);
        const int h4 = 4 * hi;

        // wait for this batch's 8 proj blocks (relaxed spin + one acquire)
        while (__hip_atomic_load(&bcnt[b], RX, SCOPE) < 8u)
            __builtin_amdgcn_s_sleep(2);
        (void)__hip_atomic_load(&bcnt[b], AQ, SCOPE);

        short8 qf[4];
        #pragma unroll
        for (int ks = 0; ks < 4; ++ks)
            qf[ks] = *reinterpret_cast<const short8*>(
                &qbf[((size_t)b * T + t0 + r) * H + ks * 16 + hi * 8]);

        unsigned int mw[4];
        #pragma unroll
        for (int kb = 0; kb < 4; ++kb)
            mw[kb] = mbits[b * 16 + (kbase >> 5) + kb];

        f32x16 sc[4];
        #pragma unroll
        for (int kb = 0; kb < 4; ++kb) {
            if (kb < nkb) {
                f32x16 a = {};
                #pragma unroll
                for (int ks = 0; ks < 4; ++ks) {
                    const short8 kf = *reinterpret_cast<const short8*>(
                        &kbf[((size_t)b * T + kbase + kb * 32 + r) * H + ks * 16 + hi * 8]);
                    a = __builtin_amdgcn_mfma_f32_32x32x16_bf16(kf, qf[ks], a, 0, 0, 0);
                }
                sc[kb] = a;
            }
        }

        float cmax = -INFINITY;
        if (diag) {
            #pragma unroll
            for (int kb = 0; kb < 4; ++kb) if (kb < nkb) {
                #pragma unroll
                for (int reg = 0; reg < 16; ++reg) {
                    const int cr = (reg & 3) + 8 * (reg >> 2) + h4;
                    float s = sc[kb][reg];
                    const bool bad = !((mw[kb] >> cr) & 1u) || (kbase + kb * 32 + cr > tq);
                    s = bad ? NEG_INF : s;
                    sc[kb][reg] = s;
                    cmax = fmaxf(cmax, s);
                }
            }
        } else {
            #pragma unroll
            for (int kb = 0; kb < 4; ++kb) {
                #pragma unroll
                for (int reg = 0; reg < 16; ++reg) {
                    const int cr = (reg & 3) + 8 * (reg >> 2) + h4;
                    float s = sc[kb][reg];
                    s = ((mw[kb] >> cr) & 1u) ? s : NEG_INF;
                    sc[kb][reg] = s;
                    cmax = fmaxf(cmax, s);
                }
            }
        }
        cmax = fmaxf(cmax, __shfl_xor(cmax, 32));
        float csum = 0.f;
        #pragma unroll
        for (int kb = 0; kb < 4; ++kb) if (kb < nkb) {
            #pragma unroll
            for (int reg = 0; reg < 16; ++reg) {
                const float p = __expf(sc[kb][reg] - cmax);
                sc[kb][reg] = p;
                csum += p;
            }
        }
        csum += __shfl_xor(csum, 32);

        f32x16 accO[2] = {};
        #pragma unroll
        for (int kb = 0; kb < 4; ++kb) if (kb < nkb) {
            unsigned int pk[8];
            #pragma unroll
            for (int j = 0; j < 8; ++j)
                pk[j] = bfpack_tr(sc[kb][2 * j], sc[kb][2 * j + 1]);
            #pragma unroll
            for (int hs = 0; hs < 2; ++hs) {
                const unsigned int p01 = pk[hs * 4 + 0], p23 = pk[hs * 4 + 1];
                const unsigned int p45 = pk[hs * 4 + 2], p67 = pk[hs * 4 + 3];
                const unsigned int sendA = hi ? p01 : p45;
                const unsigned int sendB = hi ? p23 : p67;
                const unsigned int recvA = (unsigned int)__shfl_xor((int)sendA, 32);
                const unsigned int recvB = (unsigned int)__shfl_xor((int)sendB, 32);
                union { unsigned int uu[4]; short8 s8; } aw;
                aw.uu[0] = hi ? recvA : p01;
                aw.uu[1] = hi ? recvB : p23;
                aw.uu[2] = hi ? p45 : recvA;
                aw.uu[3] = hi ? p67 : recvB;
                const int kcol = kbase + kb * 32 + hs * 16 + hi * 8;
                #pragma unroll
                for (int tile = 0; tile < 2; ++tile) {
                    const short8 vb = *reinterpret_cast<const short8*>(
                        &vT[((size_t)b * H + r + 32 * tile) * T + kcol]);
                    accO[tile] = __builtin_amdgcn_mfma_f32_32x32x16_bf16(
                        aw.s8, vb, accO[tile], 0, 0, 0);
                }
            }
        }

        #pragma unroll
        for (int reg = 0; reg < 16; ++reg) {
            const int qrow = (reg & 3) + 8 * (reg >> 2) + h4;
            unsigned short* op = &O_part[((size_t)u * 32 + qrow) * H];
            op[r]      = f2bf(accO[0][reg]);
            op[r + 32] = f2bf(accO[1][reg]);
        }
        if (hi == 0) {
            m_part[u * 32 + r] = cmax;
            l_part[u * 32 + r] = csum;
        }
        if (lane == 0)   // release: waits wave's stores, flushes, signals
            __hip_atomic_fetch_add(&gcnt[b * 4 + (qs >> 2)], 1u, RL, SCOPE);
    }

    // ================= phase C: combine (one wave per (b,g)) ==============
    if (gw < B * 4) {
        const int j = gw;                 // j = b*4+g
        const int b = j >> 2, g = j & 3;
        const unsigned int tgt = 4u * (g + 1);
        while (__hip_atomic_load(&gcnt[j], RX, SCOPE) < tgt)
            __builtin_amdgcn_s_sleep(2);
        (void)__hip_atomic_load(&gcnt[j], AQ, SCOPE);

        const int col8 = (lane & 7) * 8;
        const int cbv[4] = { 0, 16, 28, 36 };
        const int nc = g + 1;

        for (int it = 0; it < 16; ++it) {
            const int row = g * 128 + it * 8 + (lane >> 3);
            const int qs  = row >> 5;

            float mstar = -INFINITY;
            float mi[4], li[4];
            int off[4];
            #pragma unroll
            for (int c = 0; c < 4; ++c) {
                if (c < nc) {
                    const int idx = cbv[c] + qs - 4 * c;
                    off[c] = (b * NUNIT + idx) * 32 + (row & 31);
                    mi[c] = m_part[off[c]];
                    li[c] = l_part[off[c]];
                    mstar = fmaxf(mstar, mi[c]);
                }
            }
            float lsum = 0.f, fc[4];
            #pragma unroll
            for (int c = 0; c < 4; ++c) {
                if (c < nc) {
                    fc[c] = __expf(mi[c] - mstar);
                    lsum += fc[c] * li[c];
                }
            }
            const float inv = 1.f / lsum;

            float acc[8] = {};
            #pragma unroll
            for (int c = 0; c < 4; ++c) {
                if (c < nc) {
                    union { short8 v; unsigned short us[8]; } o;
                    o.v = *reinterpret_cast<const short8*>(
                        &O_part[(size_t)off[c] * H + col8]);
                    #pragma unroll
                    for (int jj = 0; jj < 8; ++jj)
                        acc[jj] += fc[c] * bf2f(o.us[jj]);
                }
            }

            float* op = &out[((size_t)b * T + row) * H + col8];
            float4 lo4 = { acc[0] * inv, acc[1] * inv, acc[2] * inv, acc[3] * inv };
            float4 hi4 = { acc[4] * inv, acc[5] * inv, acc[6] * inv, acc[7] * inv };
            *reinterpret_cast<float4*>(op)     = lo4;
            *reinterpret_cast<float4*>(op + 4) = hi4;
        }
    }
}

// ---------------------------------------------------------------------------
extern "C" void kernel_launch(void* const* d_in, const int* in_sizes, int n_in,
                              void* d_out, int out_size, void* d_ws, size_t ws_size,
                              hipStream_t stream) {
    const float* x         = (const float*)d_in[0];
    const int*   attn_mask = (const int*)d_in[1];
    const float* Wk        = (const float*)d_in[2];
    const float* Wq        = (const float*)d_in[3];
    const float* Wv        = (const float*)d_in[4];
    float* out = (float*)d_out;

    unsigned short* qbf    = (unsigned short*)d_ws;                      // 4 MB
    unsigned short* kbf    = qbf + (size_t)B * T * H;                    // 4 MB
    unsigned short* vT     = kbf + (size_t)B * T * H;                    // 4 MB
    unsigned short* WT_swz = vT  + (size_t)B * T * H;                    // 192 KB
    unsigned short* O_part = WT_swz + (size_t)PN * E;                    // 10.5 MB
    float*          m_part = (float*)(O_part + (size_t)B * NUNIT * 32 * H);
    float*          l_part = m_part + (size_t)B * NUNIT * 32;            // 328 KB ea
    unsigned int*   mbits  = (unsigned int*)(l_part + (size_t)B * NUNIT * 32); // 4 KB
    unsigned int*   sync   = mbits + (size_t)B * T / 32;                 // 1.3 KB

    // re-zero sync counters every call (graph node -> re-zeroed every replay)
    hipMemsetAsync(sync, 0, (1 + B + B * 4) * sizeof(unsigned int), stream);

    fused<<<GRID, 256, 0, stream>>>(x, Wq, Wk, Wv, attn_mask,
                                    qbf, kbf, vT, WT_swz, mbits,
                                    O_part, m_part, l_part, out, sync);
}

// Round 8
// 67.430 us; speedup vs baseline: 3.5016x; 3.5016x over previous
//
#include <hip/hip_runtime.h>

#define B 64
#define T 512
#define E 512
#define H 64
#define NEG_INF (-1e30f)

// ---------------- projection GEMM params (R6, unchanged) ----------------
#define PBM 64
#define PBK 64
#define PN 192
#define NCHK (E / PBK)

// ---------------- attention params: 64-key chunks ----------------
#define NUNIT 72      // per batch: chunk c (0..7) covers strips 2c..15 -> sum 72

using short8 = __attribute__((ext_vector_type(8))) short;
using f32x16 = __attribute__((ext_vector_type(16))) float;

__device__ __forceinline__ unsigned short f2bf(float f) {
    unsigned int u = __float_as_uint(f);
    u += 0x7fffu + ((u >> 16) & 1u);
    return (unsigned short)(u >> 16);
}
__device__ __forceinline__ float bf2f(unsigned short s) {
    return __uint_as_float((unsigned int)s << 16);
}
__device__ __forceinline__ unsigned int bfpack_tr(float lo, float hi) {
    return (__float_as_uint(hi) & 0xffff0000u) | (__float_as_uint(lo) >> 16);
}
__device__ __forceinline__ void async_copy16(const void* g, void* l) {
    __builtin_amdgcn_global_load_lds(
        (const __attribute__((address_space(1))) unsigned int*)g,
        (__attribute__((address_space(3))) unsigned int*)l, 16, 0, 0);
}

// ---------------------------------------------------------------------------
// Kernel 0: one-time prep (R6, unchanged).
// ---------------------------------------------------------------------------
__global__ __launch_bounds__(256) void prep(
    const float* __restrict__ Wq, const float* __restrict__ Wk,
    const float* __restrict__ Wv, const int* __restrict__ am,
    unsigned short* __restrict__ WT_swz, unsigned int* __restrict__ mbits)
{
    const int bid = blockIdx.x;
    if (bid < 384) {
        const int i = bid * 256 + threadIdx.x;
        const int c   = i / (PN * 64);
        const int rem = i - c * (PN * 64);
        const int row = rem >> 6;
        const int s   = rem & 63;
        const int klocal = s ^ ((row & 7) << 3);
        const int k   = c * 64 + klocal;
        const int seg = row >> 6, hh = row & 63;
        const float* W = (seg == 0) ? Wq : (seg == 1) ? Wk : Wv;
        WT_swz[i] = f2bf(W[(size_t)k * H + hh]);
    } else {
        const int i = (bid - 384) * 256 + threadIdx.x;
        const unsigned long long bal = __ballot(am[i] != 0);
        const int lane = threadIdx.x & 63;
        if (lane == 0)       mbits[i >> 5] = (unsigned int)bal;
        else if (lane == 32) mbits[i >> 5] = (unsigned int)(bal >> 32);
    }
}

// ---------------------------------------------------------------------------
// Kernel 1: fused q/k/v projection GEMM, 2-phase dbuf pipeline (R6, unchanged).
// ---------------------------------------------------------------------------
__global__ __launch_bounds__(256) void proj_gemm(
    const float* __restrict__ x,
    const unsigned short* __restrict__ WT_swz,
    unsigned short* __restrict__ qbf, unsigned short* __restrict__ kbf,
    unsigned short* __restrict__ vT)
{
    __shared__ unsigned short Xs[2][PBM * 64];
    __shared__ unsigned short Ws[2][PN * 64];

    const int tid  = threadIdx.x;
    const int wid  = tid >> 6;
    const int lane = tid & 63;
    const int hi   = lane >> 5;
    const int r    = lane & 31;
    const int row0 = blockIdx.x * PBM;

    const int mrow  = (wid >> 1) * 32 + r;
    const int cbase = (wid & 1) * 96;

    const int aBase = mrow * 128;
    const int aXor  = (mrow & 7) << 4;
    int bBase[3], bXor[3];
    #pragma unroll
    for (int nt = 0; nt < 3; ++nt) {
        const int col = cbase + nt * 32 + r;
        bBase[nt] = col * 128;
        bXor[nt]  = (col & 7) << 4;
    }
    const int xs_rr[2]  = { tid >> 3, (256 + tid) >> 3 };
    const int xs_s16[2] = { tid & 7, tid & 7 };

    f32x16 acc[3] = {};

    {
        #pragma unroll
        for (int p = 0; p < 6; ++p) {
            const int u = p * 256 + wid * 64 + lane;
            async_copy16(WT_swz + u * 8, (char*)(&Ws[0][0]) + (p * 256 + wid * 64) * 16);
        }
        #pragma unroll
        for (int p = 0; p < 2; ++p) {
            const int rr = xs_rr[p], s16 = xs_s16[p];
            const float4* src = reinterpret_cast<const float4*>(
                &x[(size_t)(row0 + rr) * E + s16 * 8]);
            const float4 a0 = src[0], a1 = src[1];
            union { unsigned short us[8]; short8 v; } pk;
            pk.us[0] = f2bf(a0.x); pk.us[1] = f2bf(a0.y);
            pk.us[2] = f2bf(a0.z); pk.us[3] = f2bf(a0.w);
            pk.us[4] = f2bf(a1.x); pk.us[5] = f2bf(a1.y);
            pk.us[6] = f2bf(a1.z); pk.us[7] = f2bf(a1.w);
            const int cb = (s16 * 16) ^ ((rr & 7) << 4);
            *reinterpret_cast<short8*>((char*)(&Xs[0][0]) + rr * 128 + cb) = pk.v;
        }
        __syncthreads();
    }

    for (int c = 0; c < NCHK; ++c) {
        const int cur = c & 1;
        const bool pre = (c + 1 < NCHK);
        float4 xa[2], xb[2];

        if (pre) {
            const unsigned short* gw = WT_swz + (size_t)(c + 1) * (PN * 64);
            #pragma unroll
            for (int p = 0; p < 6; ++p) {
                const int u = p * 256 + wid * 64 + lane;
                async_copy16(gw + u * 8,
                             (char*)(&Ws[cur ^ 1][0]) + (p * 256 + wid * 64) * 16);
            }
            const int kc = (c + 1) * PBK;
            #pragma unroll
            for (int p = 0; p < 2; ++p) {
                const float4* src = reinterpret_cast<const float4*>(
                    &x[(size_t)(row0 + xs_rr[p]) * E + kc + xs_s16[p] * 8]);
                xa[p] = src[0];
                xb[p] = src[1];
            }
        }

        #pragma unroll
        for (int ks = 0; ks < 4; ++ks) {
            const int koff = ks * 32 + hi * 16;
            const short8 a = *reinterpret_cast<const short8*>(
                (const char*)(&Xs[cur][0]) + aBase + (koff ^ aXor));
            #pragma unroll
            for (int nt = 0; nt < 3; ++nt) {
                const short8 b = *reinterpret_cast<const short8*>(
                    (const char*)(&Ws[cur][0]) + bBase[nt] + (koff ^ bXor[nt]));
                acc[nt] = __builtin_amdgcn_mfma_f32_32x32x16_bf16(a, b, acc[nt], 0, 0, 0);
            }
        }

        if (pre) {
            #pragma unroll
            for (int p = 0; p < 2; ++p) {
                const int rr = xs_rr[p], s16 = xs_s16[p];
                union { unsigned short us[8]; short8 v; } pk;
                pk.us[0] = f2bf(xa[p].x); pk.us[1] = f2bf(xa[p].y);
                pk.us[2] = f2bf(xa[p].z); pk.us[3] = f2bf(xa[p].w);
                pk.us[4] = f2bf(xb[p].x); pk.us[5] = f2bf(xb[p].y);
                pk.us[6] = f2bf(xb[p].z); pk.us[7] = f2bf(xb[p].w);
                const int cb = (s16 * 16) ^ ((rr & 7) << 4);
                *reinterpret_cast<short8*>((char*)(&Xs[cur ^ 1][0]) + rr * 128 + cb) = pk.v;
            }
        }
        __syncthreads();
    }

    #pragma unroll
    for (int nt = 0; nt < 3; ++nt) {
        const int gc  = cbase + nt * 32 + r;
        const int seg = gc >> 6;
        const int hh  = gc & 63;
        #pragma unroll
        for (int reg = 0; reg < 16; ++reg) {
            const int drow = (reg & 3) + 8 * (reg >> 2) + 4 * hi;
            const int grow = row0 + (wid >> 1) * 32 + drow;
            const float val = acc[nt][reg];
            if (seg == 0) {
                qbf[(size_t)grow * H + hh] = f2bf(val * 0.125f);
            } else if (seg == 1) {
                kbf[(size_t)grow * H + hh] = f2bf(val);
            } else {
                const int bb = grow >> 9, tt = grow & 511;
                vT[((size_t)bb * H + hh) * T + tt] = f2bf(val);
            }
        }
    }
}

// ---------------------------------------------------------------------------
// Kernel 2a: attention partials, 64-KEY chunks.  One wave per
// (batch, chunk64, strip32): chunk c in 0..7 covers strips 2c..15.
// Per batch 72 units -> grid 4608 waves (~4.5/SIMD).  Body = R6 pattern
// with nkb <= 2 (sc[2] -> lower VGPR, shorter chains).
// ---------------------------------------------------------------------------
__global__ __launch_bounds__(64) void attn_unit(
    const unsigned short* __restrict__ qbf,
    const unsigned short* __restrict__ kbf,
    const unsigned short* __restrict__ vT,
    const unsigned int* __restrict__ mbits,
    unsigned short* __restrict__ O_part,
    float* __restrict__ m_part, float* __restrict__ l_part)
{
    const int lane = threadIdx.x;
    const int hi = lane >> 5, r = lane & 31;
    const int h4 = 4 * hi;

    const int u = blockIdx.x;
    const int b = u / NUNIT;
    const int t = u - b * NUNIT;
    // chunk offsets: off_c = c*(17-c) = 0,16,30,42,52,60,66,70
    int c;
    if (t < 16)      c = 0;
    else if (t < 30) c = 1;
    else if (t < 42) c = 2;
    else if (t < 52) c = 3;
    else if (t < 60) c = 4;
    else if (t < 66) c = 5;
    else if (t < 70) c = 6;
    else             c = 7;
    const int qs    = 2 * c + (t - c * (17 - c));
    const int t0    = qs * 32;
    const int kbase = c * 64;
    const int tq    = t0 + r;
    const int nkb   = min(2, ((t0 + 31 - kbase) >> 5) + 1);
    const bool diag = (kbase + 64 > t0);

    short8 qf[4];
    #pragma unroll
    for (int ks = 0; ks < 4; ++ks)
        qf[ks] = *reinterpret_cast<const short8*>(
            &qbf[((size_t)b * T + t0 + r) * H + ks * 16 + hi * 8]);

    unsigned int mw[2];
    #pragma unroll
    for (int kb = 0; kb < 2; ++kb)
        mw[kb] = mbits[b * 16 + (kbase >> 5) + kb];

    // ---- QK^T swapped, K straight from global ----
    f32x16 sc[2];
    #pragma unroll
    for (int kb = 0; kb < 2; ++kb) {
        if (kb < nkb) {
            f32x16 a = {};
            #pragma unroll
            for (int ks = 0; ks < 4; ++ks) {
                const short8 kf = *reinterpret_cast<const short8*>(
                    &kbf[((size_t)b * T + kbase + kb * 32 + r) * H + ks * 16 + hi * 8]);
                a = __builtin_amdgcn_mfma_f32_32x32x16_bf16(kf, qf[ks], a, 0, 0, 0);
            }
            sc[kb] = a;
        }
    }

    // ---- mask + local softmax ----
    float cmax = -INFINITY;
    if (diag) {
        #pragma unroll
        for (int kb = 0; kb < 2; ++kb) if (kb < nkb) {
            #pragma unroll
            for (int reg = 0; reg < 16; ++reg) {
                const int cr = (reg & 3) + 8 * (reg >> 2) + h4;
                float s = sc[kb][reg];
                const bool bad = !((mw[kb] >> cr) & 1u) || (kbase + kb * 32 + cr > tq);
                s = bad ? NEG_INF : s;
                sc[kb][reg] = s;
                cmax = fmaxf(cmax, s);
            }
        }
    } else {
        #pragma unroll
        for (int kb = 0; kb < 2; ++kb) {
            #pragma unroll
            for (int reg = 0; reg < 16; ++reg) {
                const int cr = (reg & 3) + 8 * (reg >> 2) + h4;
                float s = sc[kb][reg];
                s = ((mw[kb] >> cr) & 1u) ? s : NEG_INF;
                sc[kb][reg] = s;
                cmax = fmaxf(cmax, s);
            }
        }
    }
    cmax = fmaxf(cmax, __shfl_xor(cmax, 32));
    float csum = 0.f;
    #pragma unroll
    for (int kb = 0; kb < 2; ++kb) if (kb < nkb) {
        #pragma unroll
        for (int reg = 0; reg < 16; ++reg) {
            const float p = __expf(sc[kb][reg] - cmax);
            sc[kb][reg] = p;
            csum += p;
        }
    }
    csum += __shfl_xor(csum, 32);

    // ---- PV ----
    f32x16 accO[2] = {};
    #pragma unroll
    for (int kb = 0; kb < 2; ++kb) if (kb < nkb) {
        unsigned int pk[8];
        #pragma unroll
        for (int j = 0; j < 8; ++j)
            pk[j] = bfpack_tr(sc[kb][2 * j], sc[kb][2 * j + 1]);
        #pragma unroll
        for (int hs = 0; hs < 2; ++hs) {
            const unsigned int p01 = pk[hs * 4 + 0], p23 = pk[hs * 4 + 1];
            const unsigned int p45 = pk[hs * 4 + 2], p67 = pk[hs * 4 + 3];
            const unsigned int sendA = hi ? p01 : p45;
            const unsigned int sendB = hi ? p23 : p67;
            const unsigned int recvA = (unsigned int)__shfl_xor((int)sendA, 32);
            const unsigned int recvB = (unsigned int)__shfl_xor((int)sendB, 32);
            union { unsigned int uu[4]; short8 s8; } aw;
            aw.uu[0] = hi ? recvA : p01;
            aw.uu[1] = hi ? recvB : p23;
            aw.uu[2] = hi ? p45 : recvA;
            aw.uu[3] = hi ? p67 : recvB;
            const int kcol = kbase + kb * 32 + hs * 16 + hi * 8;
            #pragma unroll
            for (int tile = 0; tile < 2; ++tile) {
                const short8 vb = *reinterpret_cast<const short8*>(
                    &vT[((size_t)b * H + r + 32 * tile) * T + kcol]);
                accO[tile] = __builtin_amdgcn_mfma_f32_32x32x16_bf16(
                    aw.s8, vb, accO[tile], 0, 0, 0);
            }
        }
    }

    // ---- write partials ----
    #pragma unroll
    for (int reg = 0; reg < 16; ++reg) {
        const int qrow = (reg & 3) + 8 * (reg >> 2) + h4;
        unsigned short* op = &O_part[((size_t)u * 32 + qrow) * H];
        op[r]      = f2bf(accO[0][reg]);
        op[r + 32] = f2bf(accO[1][reg]);
    }
    if (hi == 0) {
        m_part[u * 32 + r] = cmax;
        l_part[u * 32 + r] = csum;
    }
}

// ---------------------------------------------------------------------------
// Kernel 2b: combine up to 8 chunk partials per row and normalize.
// One block per (batch, 128-row group).
// ---------------------------------------------------------------------------
__global__ __launch_bounds__(256) void attn_comb(
    const unsigned short* __restrict__ O_part,
    const float* __restrict__ m_part, const float* __restrict__ l_part,
    float* __restrict__ out)
{
    const int b    = blockIdx.x >> 2;
    const int g    = blockIdx.x & 3;
    const int tid  = threadIdx.x;
    const int col8 = (tid & 7) * 8;

    #pragma unroll
    for (int pass = 0; pass < 4; ++pass) {
        const int row = g * 128 + pass * 32 + (tid >> 3);
        const int qs  = row >> 5;               // strip index
        const int nc  = (qs >> 1) + 1;          // chunks for this strip

        float mstar = -INFINITY;
        float mi[8], li[8];
        int off[8];
        #pragma unroll
        for (int c = 0; c < 8; ++c) {
            if (c < nc) {
                const int idx = c * (17 - c) + (qs - 2 * c);
                off[c] = (b * NUNIT + idx) * 32 + (row & 31);
                mi[c] = m_part[off[c]];
                li[c] = l_part[off[c]];
                mstar = fmaxf(mstar, mi[c]);
            }
        }
        float lsum = 0.f, fc[8];
        #pragma unroll
        for (int c = 0; c < 8; ++c) {
            if (c < nc) {
                fc[c] = __expf(mi[c] - mstar);
                lsum += fc[c] * li[c];
            }
        }
        const float inv = 1.f / lsum;

        float acc[8] = {};
        #pragma unroll
        for (int c = 0; c < 8; ++c) {
            if (c < nc) {
                union { short8 v; unsigned short us[8]; } o;
                o.v = *reinterpret_cast<const short8*>(
                    &O_part[(size_t)off[c] * H + col8]);
                #pragma unroll
                for (int j = 0; j < 8; ++j)
                    acc[j] += fc[c] * bf2f(o.us[j]);
            }
        }

        float* op = &out[((size_t)b * T + row) * H + col8];
        float4 lo4 = { acc[0] * inv, acc[1] * inv, acc[2] * inv, acc[3] * inv };
        float4 hi4 = { acc[4] * inv, acc[5] * inv, acc[6] * inv, acc[7] * inv };
        *reinterpret_cast<float4*>(op)     = lo4;
        *reinterpret_cast<float4*>(op + 4) = hi4;
    }
}

// ---------------------------------------------------------------------------
extern "C" void kernel_launch(void* const* d_in, const int* in_sizes, int n_in,
                              void* d_out, int out_size, void* d_ws, size_t ws_size,
                              hipStream_t stream) {
    const float* x         = (const float*)d_in[0];
    const int*   attn_mask = (const int*)d_in[1];
    const float* Wk        = (const float*)d_in[2];
    const float* Wq        = (const float*)d_in[3];
    const float* Wv        = (const float*)d_in[4];
    float* out = (float*)d_out;

    unsigned short* qbf    = (unsigned short*)d_ws;                      // 4 MB
    unsigned short* kbf    = qbf + (size_t)B * T * H;                    // 4 MB
    unsigned short* vT     = kbf + (size_t)B * T * H;                    // 4 MB
    unsigned short* WT_swz = vT  + (size_t)B * T * H;                    // 192 KB
    unsigned short* O_part = WT_swz + (size_t)PN * E;                    // 18.9 MB
    float*          m_part = (float*)(O_part + (size_t)B * NUNIT * 32 * H);
    float*          l_part = m_part + (size_t)B * NUNIT * 32;            // 590 KB ea
    unsigned int*   mbits  = (unsigned int*)(l_part + (size_t)B * NUNIT * 32);

    prep<<<512, 256, 0, stream>>>(Wq, Wk, Wv, attn_mask, WT_swz, mbits);
    proj_gemm<<<(B * T) / PBM, 256, 0, stream>>>(x, WT_swz, qbf, kbf, vT);
    attn_unit<<<B * NUNIT, 64, 0, stream>>>(qbf, kbf, vT, mbits,
                                            O_part, m_part, l_part);
    attn_comb<<<B * 4, 256, 0, stream>>>(O_part, m_part, l_part, out);
}

// Round 9
// 53.055 us; speedup vs baseline: 4.4504x; 1.2710x over previous
//
#include <hip/hip_runtime.h>

#define B 64
#define T 512
#define E 512
#define H 64
#define NEG_INF (-1e30f)

// ---------------- projection GEMM params (R6, unchanged) ----------------
#define PBM 64
#define PBK 64
#define PN 192
#define NCHK (E / PBK)

using short8 = __attribute__((ext_vector_type(8))) short;
using f32x16 = __attribute__((ext_vector_type(16))) float;

__device__ __forceinline__ unsigned short f2bf(float f) {
    unsigned int u = __float_as_uint(f);
    u += 0x7fffu + ((u >> 16) & 1u);
    return (unsigned short)(u >> 16);
}
__device__ __forceinline__ unsigned int bfpack_tr(float lo, float hi) {
    return (__float_as_uint(hi) & 0xffff0000u) | (__float_as_uint(lo) >> 16);
}
__device__ __forceinline__ void async_copy16(const void* g, void* l) {
    __builtin_amdgcn_global_load_lds(
        (const __attribute__((address_space(1))) unsigned int*)g,
        (__attribute__((address_space(3))) unsigned int*)l, 16, 0, 0);
}

// ---------------------------------------------------------------------------
// Kernel 0: one-time prep (unchanged).
// ---------------------------------------------------------------------------
__global__ __launch_bounds__(256) void prep(
    const float* __restrict__ Wq, const float* __restrict__ Wk,
    const float* __restrict__ Wv, const int* __restrict__ am,
    unsigned short* __restrict__ WT_swz, unsigned int* __restrict__ mbits)
{
    const int bid = blockIdx.x;
    if (bid < 384) {
        const int i = bid * 256 + threadIdx.x;
        const int c   = i / (PN * 64);
        const int rem = i - c * (PN * 64);
        const int row = rem >> 6;
        const int s   = rem & 63;
        const int klocal = s ^ ((row & 7) << 3);
        const int k   = c * 64 + klocal;
        const int seg = row >> 6, hh = row & 63;
        const float* W = (seg == 0) ? Wq : (seg == 1) ? Wk : Wv;
        WT_swz[i] = f2bf(W[(size_t)k * H + hh]);
    } else {
        const int i = (bid - 384) * 256 + threadIdx.x;
        const unsigned long long bal = __ballot(am[i] != 0);
        const int lane = threadIdx.x & 63;
        if (lane == 0)       mbits[i >> 5] = (unsigned int)bal;
        else if (lane == 32) mbits[i >> 5] = (unsigned int)(bal >> 32);
    }
}

// ---------------------------------------------------------------------------
// Kernel 1: fused q/k/v projection GEMM, 2-phase dbuf pipeline (unchanged).
// ---------------------------------------------------------------------------
__global__ __launch_bounds__(256) void proj_gemm(
    const float* __restrict__ x,
    const unsigned short* __restrict__ WT_swz,
    unsigned short* __restrict__ qbf, unsigned short* __restrict__ kbf,
    unsigned short* __restrict__ vT)
{
    __shared__ unsigned short Xs[2][PBM * 64];
    __shared__ unsigned short Ws[2][PN * 64];

    const int tid  = threadIdx.x;
    const int wid  = tid >> 6;
    const int lane = tid & 63;
    const int hi   = lane >> 5;
    const int r    = lane & 31;
    const int row0 = blockIdx.x * PBM;

    const int mrow  = (wid >> 1) * 32 + r;
    const int cbase = (wid & 1) * 96;

    const int aBase = mrow * 128;
    const int aXor  = (mrow & 7) << 4;
    int bBase[3], bXor[3];
    #pragma unroll
    for (int nt = 0; nt < 3; ++nt) {
        const int col = cbase + nt * 32 + r;
        bBase[nt] = col * 128;
        bXor[nt]  = (col & 7) << 4;
    }
    const int xs_rr[2]  = { tid >> 3, (256 + tid) >> 3 };
    const int xs_s16[2] = { tid & 7, tid & 7 };

    f32x16 acc[3] = {};

    {
        #pragma unroll
        for (int p = 0; p < 6; ++p) {
            const int u = p * 256 + wid * 64 + lane;
            async_copy16(WT_swz + u * 8, (char*)(&Ws[0][0]) + (p * 256 + wid * 64) * 16);
        }
        #pragma unroll
        for (int p = 0; p < 2; ++p) {
            const int rr = xs_rr[p], s16 = xs_s16[p];
            const float4* src = reinterpret_cast<const float4*>(
                &x[(size_t)(row0 + rr) * E + s16 * 8]);
            const float4 a0 = src[0], a1 = src[1];
            union { unsigned short us[8]; short8 v; } pk;
            pk.us[0] = f2bf(a0.x); pk.us[1] = f2bf(a0.y);
            pk.us[2] = f2bf(a0.z); pk.us[3] = f2bf(a0.w);
            pk.us[4] = f2bf(a1.x); pk.us[5] = f2bf(a1.y);
            pk.us[6] = f2bf(a1.z); pk.us[7] = f2bf(a1.w);
            const int cb = (s16 * 16) ^ ((rr & 7) << 4);
            *reinterpret_cast<short8*>((char*)(&Xs[0][0]) + rr * 128 + cb) = pk.v;
        }
        __syncthreads();
    }

    for (int c = 0; c < NCHK; ++c) {
        const int cur = c & 1;
        const bool pre = (c + 1 < NCHK);
        float4 xa[2], xb[2];

        if (pre) {
            const unsigned short* gw = WT_swz + (size_t)(c + 1) * (PN * 64);
            #pragma unroll
            for (int p = 0; p < 6; ++p) {
                const int u = p * 256 + wid * 64 + lane;
                async_copy16(gw + u * 8,
                             (char*)(&Ws[cur ^ 1][0]) + (p * 256 + wid * 64) * 16);
            }
            const int kc = (c + 1) * PBK;
            #pragma unroll
            for (int p = 0; p < 2; ++p) {
                const float4* src = reinterpret_cast<const float4*>(
                    &x[(size_t)(row0 + xs_rr[p]) * E + kc + xs_s16[p] * 8]);
                xa[p] = src[0];
                xb[p] = src[1];
            }
        }

        #pragma unroll
        for (int ks = 0; ks < 4; ++ks) {
            const int koff = ks * 32 + hi * 16;
            const short8 a = *reinterpret_cast<const short8*>(
                (const char*)(&Xs[cur][0]) + aBase + (koff ^ aXor));
            #pragma unroll
            for (int nt = 0; nt < 3; ++nt) {
                const short8 b = *reinterpret_cast<const short8*>(
                    (const char*)(&Ws[cur][0]) + bBase[nt] + (koff ^ bXor[nt]));
                acc[nt] = __builtin_amdgcn_mfma_f32_32x32x16_bf16(a, b, acc[nt], 0, 0, 0);
            }
        }

        if (pre) {
            #pragma unroll
            for (int p = 0; p < 2; ++p) {
                const int rr = xs_rr[p], s16 = xs_s16[p];
                union { unsigned short us[8]; short8 v; } pk;
                pk.us[0] = f2bf(xa[p].x); pk.us[1] = f2bf(xa[p].y);
                pk.us[2] = f2bf(xa[p].z); pk.us[3] = f2bf(xa[p].w);
                pk.us[4] = f2bf(xb[p].x); pk.us[5] = f2bf(xb[p].y);
                pk.us[6] = f2bf(xb[p].z); pk.us[7] = f2bf(xb[p].w);
                const int cb = (s16 * 16) ^ ((rr & 7) << 4);
                *reinterpret_cast<short8*>((char*)(&Xs[cur ^ 1][0]) + rr * 128 + cb) = pk.v;
            }
        }
        __syncthreads();
    }

    #pragma unroll
    for (int nt = 0; nt < 3; ++nt) {
        const int gc  = cbase + nt * 32 + r;
        const int seg = gc >> 6;
        const int hh  = gc & 63;
        #pragma unroll
        for (int reg = 0; reg < 16; ++reg) {
            const int drow = (reg & 3) + 8 * (reg >> 2) + 4 * hi;
            const int grow = row0 + (wid >> 1) * 32 + drow;
            const float val = acc[nt][reg];
            if (seg == 0) {
                qbf[(size_t)grow * H + hh] = f2bf(val * 0.125f);
            } else if (seg == 1) {
                kbf[(size_t)grow * H + hh] = f2bf(val);
            } else {
                const int bb = grow >> 9, tt = grow & 511;
                vT[((size_t)bb * H + hh) * T + tt] = f2bf(val);
            }
        }
    }
}

// ---------------------------------------------------------------------------
// Kernel 2: ONLINE flash attention, one wave per (batch, 32-row q strip).
// 1024 one-wave blocks, no LDS, no barriers, no partials: K/V fragments read
// directly from global (L2-hot via XCD packing: bid&7 == b&7 keeps all 16
// strips of a batch on one XCD), online softmax lane-local (swapped QK^T),
// normalized result written straight to out.  Strips issued big-first.
// ---------------------------------------------------------------------------
__global__ __launch_bounds__(64) void attn_online(
    const unsigned short* __restrict__ qbf,
    const unsigned short* __restrict__ kbf,
    const unsigned short* __restrict__ vT,
    const unsigned int* __restrict__ mbits,
    float* __restrict__ out)
{
    const int lane = threadIdx.x;
    const int hi = lane >> 5, r = lane & 31;
    const int h4 = 4 * hi;

    // XCD packing: xcd = bid&7 = b&7; k = bid>>3; b = ((k>>4)<<3)|xcd;
    // strip = 15-(k&15)  (big strips first per XCD queue)
    const int bid = blockIdx.x;
    const int k   = bid >> 3;
    const int b   = ((k >> 4) << 3) | (bid & 7);
    const int s   = 15 - (k & 15);
    const int t0  = s * 32;
    const int tq  = t0 + r;

    // Q fragments (pre-scaled by 1/8 in proj)
    short8 qf[4];
    #pragma unroll
    for (int ks = 0; ks < 4; ++ks)
        qf[ks] = *reinterpret_cast<const short8*>(
            &qbf[((size_t)b * T + t0 + r) * H + ks * 16 + hi * 8]);

    f32x16 accO[2] = {};
    float m = -INFINITY, l = 0.f;

    // prefetch K fragments for block 0
    short8 kf[4];
    #pragma unroll
    for (int ks = 0; ks < 4; ++ks)
        kf[ks] = *reinterpret_cast<const short8*>(
            &kbf[((size_t)b * T + r) * H + ks * 16 + hi * 8]);

    for (int j = 0; j <= s; ++j) {
        // V fragments for this block: issue early (latency under QK/softmax)
        short8 vb[4];
        #pragma unroll
        for (int hs = 0; hs < 2; ++hs)
            #pragma unroll
            for (int tile = 0; tile < 2; ++tile)
                vb[hs * 2 + tile] = *reinterpret_cast<const short8*>(
                    &vT[((size_t)b * H + r + 32 * tile) * T + 32 * j + hs * 16 + hi * 8]);

        // prefetch next block's K fragments
        short8 kn[4];
        if (j < s) {
            #pragma unroll
            for (int ks = 0; ks < 4; ++ks)
                kn[ks] = *reinterpret_cast<const short8*>(
                    &kbf[((size_t)b * T + 32 * (j + 1) + r) * H + ks * 16 + hi * 8]);
        }

        // ---- QK^T swapped: lane owns q-row t0+r; regs cover 16 keys ----
        f32x16 sc = {};
        #pragma unroll
        for (int ks = 0; ks < 4; ++ks)
            sc = __builtin_amdgcn_mfma_f32_32x32x16_bf16(kf[ks], qf[ks], sc, 0, 0, 0);
        #pragma unroll
        for (int ks = 0; ks < 4; ++ks) kf[ks] = kn[ks];

        // ---- mask ----
        const unsigned int mw = mbits[b * 16 + j];
        float cmax = -INFINITY;
        if (j == s) {   // diagonal block: causal + pad mask
            #pragma unroll
            for (int reg = 0; reg < 16; ++reg) {
                const int cr = (reg & 3) + 8 * (reg >> 2) + h4;
                float v = sc[reg];
                const bool bad = !((mw >> cr) & 1u) || (32 * j + cr > tq);
                v = bad ? NEG_INF : v;
                sc[reg] = v;
                cmax = fmaxf(cmax, v);
            }
        } else {        // full block: pad mask only
            #pragma unroll
            for (int reg = 0; reg < 16; ++reg) {
                const int cr = (reg & 3) + 8 * (reg >> 2) + h4;
                float v = sc[reg];
                v = ((mw >> cr) & 1u) ? v : NEG_INF;
                sc[reg] = v;
                cmax = fmaxf(cmax, v);
            }
        }
        cmax = fmaxf(cmax, __shfl_xor(cmax, 32));

        // ---- online update (skip rescale when max didn't grow) ----
        const float m_new = fmaxf(m, cmax);
        if (!__all(cmax <= m)) {
            const float scale = __expf(m - m_new);   // exp(-inf)=0 first block
            f32x16 scf;
            #pragma unroll
            for (int reg = 0; reg < 16; ++reg)
                scf[reg] = __shfl(scale, (reg & 3) + 8 * (reg >> 2) + h4);
            #pragma unroll
            for (int reg = 0; reg < 16; ++reg) {
                accO[0][reg] *= scf[reg];
                accO[1][reg] *= scf[reg];
            }
            l *= scale;
        }
        m = m_new;

        float csum = 0.f;
        #pragma unroll
        for (int reg = 0; reg < 16; ++reg) {
            const float p = __expf(sc[reg] - m_new);
            sc[reg] = p;
            csum += p;
        }
        csum += __shfl_xor(csum, 32);
        l += csum;

        // ---- PV: build P bf16 A-frags in-register, accumulate ----
        unsigned int pk[8];
        #pragma unroll
        for (int jj = 0; jj < 8; ++jj)
            pk[jj] = bfpack_tr(sc[2 * jj], sc[2 * jj + 1]);
        #pragma unroll
        for (int hs = 0; hs < 2; ++hs) {
            const unsigned int p01 = pk[hs * 4 + 0], p23 = pk[hs * 4 + 1];
            const unsigned int p45 = pk[hs * 4 + 2], p67 = pk[hs * 4 + 3];
            const unsigned int sendA = hi ? p01 : p45;
            const unsigned int sendB = hi ? p23 : p67;
            const unsigned int recvA = (unsigned int)__shfl_xor((int)sendA, 32);
            const unsigned int recvB = (unsigned int)__shfl_xor((int)sendB, 32);
            union { unsigned int uu[4]; short8 s8; } aw;
            aw.uu[0] = hi ? recvA : p01;
            aw.uu[1] = hi ? recvB : p23;
            aw.uu[2] = hi ? p45 : recvA;
            aw.uu[3] = hi ? p67 : recvB;
            #pragma unroll
            for (int tile = 0; tile < 2; ++tile)
                accO[tile] = __builtin_amdgcn_mfma_f32_32x32x16_bf16(
                    aw.s8, vb[hs * 2 + tile], accO[tile], 0, 0, 0);
        }
    }

    // ---- epilogue: normalize and store ----
    const float inv = 1.f / l;
    #pragma unroll
    for (int reg = 0; reg < 16; ++reg) {
        const int qrow = (reg & 3) + 8 * (reg >> 2) + h4;
        const float f = __shfl(inv, qrow);
        float* op = &out[((size_t)b * T + t0 + qrow) * H];
        op[r]      = accO[0][reg] * f;
        op[r + 32] = accO[1][reg] * f;
    }
}

// ---------------------------------------------------------------------------
extern "C" void kernel_launch(void* const* d_in, const int* in_sizes, int n_in,
                              void* d_out, int out_size, void* d_ws, size_t ws_size,
                              hipStream_t stream) {
    const float* x         = (const float*)d_in[0];
    const int*   attn_mask = (const int*)d_in[1];
    const float* Wk        = (const float*)d_in[2];
    const float* Wq        = (const float*)d_in[3];
    const float* Wv        = (const float*)d_in[4];
    float* out = (float*)d_out;

    unsigned short* qbf    = (unsigned short*)d_ws;                      // 4 MB
    unsigned short* kbf    = qbf + (size_t)B * T * H;                    // 4 MB
    unsigned short* vT     = kbf + (size_t)B * T * H;                    // 4 MB
    unsigned short* WT_swz = vT  + (size_t)B * T * H;                    // 192 KB
    unsigned int*   mbits  = (unsigned int*)(WT_swz + (size_t)PN * E);   // 4 KB

    prep<<<512, 256, 0, stream>>>(Wq, Wk, Wv, attn_mask, WT_swz, mbits);
    proj_gemm<<<(B * T) / PBM, 256, 0, stream>>>(x, WT_swz, qbf, kbf, vT);
    attn_online<<<B * 16, 64, 0, stream>>>(qbf, kbf, vT, mbits, out);
}